// Round 11
// baseline (207.090 us; speedup 1.0000x reference)
//
#include <hip/hip_runtime.h>
#include <hip/hip_bf16.h>

// MultiHeadSelfAttention: B=2, T=2048, C=1024, H=16, D=64
// Pipeline: conv_bf16, transp_conv x2, gemm<MODE2> (qkv + fused V-transpose),
//           attn v4 (kv-split waves: P in registers, 4x less LDS read traffic),
//           gemm<MODE1,BN=64> (proj).
// bf16 MFMA, fp32 accum.

typedef unsigned short u16;
using bf16x8 = __attribute__((ext_vector_type(8))) short;
using bf16x4 = __attribute__((ext_vector_type(4))) short;
using f32x4  = __attribute__((ext_vector_type(4))) float;

#define T_SEQ 2048
#define CDIM  1024

#define QSCALE 0.18033688011112042f   // 0.125*log2(e), folded into W_attn Q-rows

#if __has_builtin(__builtin_amdgcn_exp2f)
#define EXP2(x) __builtin_amdgcn_exp2f(x)
#else
#define EXP2(x) __expf((x) * 0.6931471805599453f)
#endif

__device__ inline u16 f2bf(float f) {
  __hip_bfloat16 h = __float2bfloat16(f);
  return *reinterpret_cast<u16*>(&h);
}
__device__ inline unsigned pk2bf(float a, float b) {
  return (unsigned)f2bf(a) | ((unsigned)f2bf(b) << 16);
}
__device__ inline float bf2f(u16 v) { return __uint_as_float((unsigned)v << 16); }

// K=16 bf16 MFMA (A,B: 4 bf16/lane; layout row/col=l16, k=lh*4+j)
__device__ inline f32x4 mfma16(bf16x4 a, bf16x4 b, f32x4 c) {
#if __has_builtin(__builtin_amdgcn_mfma_f32_16x16x16_bf16)
  return __builtin_amdgcn_mfma_f32_16x16x16_bf16(a, b, c, 0, 0, 0);
#elif __has_builtin(__builtin_amdgcn_mfma_f32_16x16x16bf16_1k)
  return __builtin_amdgcn_mfma_f32_16x16x16bf16_1k(a, b, c, 0, 0, 0);
#else
  asm volatile("v_mfma_f32_16x16x16_bf16 %0, %1, %2, %0" : "+v"(c) : "v"(a), "v"(b));
  return c;
#endif
}

// async global->LDS, 16B per lane. LDS dest = l + lane*16B (l wave-uniform).
__device__ inline void gload_lds16(const u16* g, u16* l) {
  __builtin_amdgcn_global_load_lds((const __attribute__((address_space(1))) void*)g,
                                   (__attribute__((address_space(3))) void*)l, 16, 0, 0);
}

// XOR swizzle for [R][64] bf16 tiles (128B rows). Returns u16 index.
__device__ inline int swz128(int r, int c) {
  return (((r << 7) + (c << 1)) ^ ((r & 7) << 4)) >> 1;
}

// ---------------- fp32 -> bf16 elementwise ----------------
__global__ __launch_bounds__(256) void conv_bf16_kernel(const float* __restrict__ in,
                                                        u16* __restrict__ out, int n4) {
  int idx = blockIdx.x * 256 + threadIdx.x;
  if (idx >= n4) return;
  float4 v = reinterpret_cast<const float4*>(in)[idx];
  ushort4 o;
  o.x = f2bf(v.x); o.y = f2bf(v.y); o.z = f2bf(v.z); o.w = f2bf(v.w);
  reinterpret_cast<ushort4*>(out)[idx] = o;
}

// ---------------- fp32 [R][N] -> bf16 [N][R] transpose-convert (+row scale) ----------------
__global__ __launch_bounds__(256) void transp_conv_kernel(const float* __restrict__ in,
                                                          u16* __restrict__ out, int R, int N,
                                                          int scale_rows, float scale) {
  __shared__ float tile[32][33];
  int nbx = N >> 5;
  int bx = blockIdx.x % nbx, by = blockIdx.x / nbx;
  int tx = threadIdx.x & 31, ty = threadIdx.x >> 5;
#pragma unroll
  for (int rr = ty; rr < 32; rr += 8)
    tile[rr][tx] = in[(long)(by * 32 + rr) * N + bx * 32 + tx];
  __syncthreads();
#pragma unroll
  for (int rr = ty; rr < 32; rr += 8) {
    float s = (bx * 32 + rr) < scale_rows ? scale : 1.0f;
    out[(long)(bx * 32 + rr) * R + by * 32 + tx] = f2bf(tile[tx][rr] * s);
  }
}

// ---------------- bf16 GEMM: C[M,N] = A[M,K] * Bt[N,K]^T ----------------
// BM=128, BN in {128,64}, BK=32, 4 waves. 2-phase dbuf global_load_lds, tm-inner map.
// MODE 0: bf16 C. MODE 1: f32 C, swapped operands -> float4 epilogue.
// MODE 2: qkv fused (tn<16 bf16 C; tn>=16 V region transposed to vT).
template <int MODE, int BN>
__global__ __launch_bounds__(256) void gemm_bt_kernel(const u16* __restrict__ A,
                                                      const u16* __restrict__ Bt,
                                                      void* __restrict__ C,
                                                      u16* __restrict__ vT,
                                                      int N, int K) {
  constexpr int NJ = BN / 32;
  constexpr int WN = BN / 2;
  __shared__ u16 As[2][128 * 32];
  __shared__ u16 Bs[2][BN * 32];
  const int tid = threadIdx.x;
  const int lane = tid & 63, wid = tid >> 6;
  const int l16 = lane & 15, lh = lane >> 4;
  const int wm = wid >> 1, wn = wid & 1;
  const int tm = blockIdx.x & 31;
  const int tn = blockIdx.x >> 5;

  f32x4 acc[4][NJ];
#pragma unroll
  for (int i = 0; i < 4; ++i)
#pragma unroll
    for (int j = 0; j < NJ; ++j)
      acc[i][j] = f32x4{0.f, 0.f, 0.f, 0.f};

  const long aRow = (long)(tm * 128 + wid * 16 + (lane >> 2)) * K + (lane & 3) * 8;
  const long bRow = (long)(tn * BN + wid * 16 + (lane >> 2)) * K + (lane & 3) * 8;
  const long rstep = (long)64 * K;
  const int ldsOff = wid * 512;

  gload_lds16(A + aRow, As[0] + ldsOff);
  gload_lds16(A + aRow + rstep, As[0] + ldsOff + 2048);
  gload_lds16(Bt + bRow, Bs[0] + ldsOff);
  if (BN == 128) gload_lds16(Bt + bRow + rstep, Bs[0] + ldsOff + 2048);
  __syncthreads();

  int cur = 0;
  for (int k0 = 0; k0 < K; k0 += 32) {
    if (k0 + 32 < K) {
      gload_lds16(A + aRow + k0 + 32, As[cur ^ 1] + ldsOff);
      gload_lds16(A + aRow + rstep + k0 + 32, As[cur ^ 1] + ldsOff + 2048);
      gload_lds16(Bt + bRow + k0 + 32, Bs[cur ^ 1] + ldsOff);
      if (BN == 128) gload_lds16(Bt + bRow + rstep + k0 + 32, Bs[cur ^ 1] + ldsOff + 2048);
    }
    bf16x8 af[4], bfr[NJ];
#pragma unroll
    for (int i = 0; i < 4; ++i)
      af[i] = *reinterpret_cast<const bf16x8*>(&As[cur][(wm * 64 + i * 16 + l16) * 32 + lh * 8]);
#pragma unroll
    for (int j = 0; j < NJ; ++j)
      bfr[j] = *reinterpret_cast<const bf16x8*>(&Bs[cur][(wn * WN + j * 16 + l16) * 32 + lh * 8]);
#pragma unroll
    for (int i = 0; i < 4; ++i)
#pragma unroll
      for (int j = 0; j < NJ; ++j) {
        if (MODE == 1)
          acc[i][j] = __builtin_amdgcn_mfma_f32_16x16x32_bf16(bfr[j], af[i], acc[i][j], 0, 0, 0);
        else
          acc[i][j] = __builtin_amdgcn_mfma_f32_16x16x32_bf16(af[i], bfr[j], acc[i][j], 0, 0, 0);
      }
    __syncthreads();
    cur ^= 1;
  }

  if (MODE == 1) {
#pragma unroll
    for (int i = 0; i < 4; ++i) {
#pragma unroll
      for (int j = 0; j < NJ; ++j) {
        long row = tm * 128 + wm * 64 + i * 16 + l16;
        long col = tn * BN + wn * WN + j * 16 + lh * 4;
        *reinterpret_cast<float4*>(reinterpret_cast<float*>(C) + row * N + col) =
            float4{acc[i][j][0], acc[i][j][1], acc[i][j][2], acc[i][j][3]};
      }
    }
    return;
  }

  if (MODE == 2 && tn >= 16) {
    const int bsel = tm >> 4;
    const int t0 = (tm & 15) * 128 + wm * 64 + lh * 4;
#pragma unroll
    for (int i = 0; i < 4; ++i) {
#pragma unroll
      for (int j = 0; j < NJ; ++j) {
        const int h = 2 * (tn - 16) + wn;
        const int d = j * 16 + l16;
        u16* dst = vT + (long)((bsel * 16 + h) * 64 + d) * T_SEQ + t0 + i * 16;
        uint2 w2;
        w2.x = pk2bf(acc[i][j][0], acc[i][j][1]);
        w2.y = pk2bf(acc[i][j][2], acc[i][j][3]);
        *reinterpret_cast<uint2*>(dst) = w2;
      }
    }
    return;
  }

#pragma unroll
  for (int i = 0; i < 4; ++i) {
#pragma unroll
    for (int j = 0; j < NJ; ++j) {
#pragma unroll
      for (int r = 0; r < 4; ++r) {
        long row = tm * 128 + wm * 64 + i * 16 + lh * 4 + r;
        long col = tn * BN + wn * WN + j * 16 + l16;
        reinterpret_cast<u16*>(C)[row * N + col] = f2bf(acc[i][j][r]);
      }
    }
  }
}

// ---------------- V transpose (fallback when ws too small for fused path) ----------------
__global__ __launch_bounds__(256) void vtrans_kernel(const u16* __restrict__ qkv,
                                                     u16* __restrict__ vT) {
  __shared__ u16 Ts[64 * 64];
  const int tid = threadIdx.x;
  const int bid = blockIdx.x;
  const int tt = bid & 31, bh = bid >> 5;
  const int b = bh >> 4, h = bh & 15;
  const int sr = tid >> 2, sc = (tid & 3) * 16;
  const u16* src = qkv + (long)(b * T_SEQ + tt * 64 + sr) * 3072 + 2 * CDIM + h * 64 + sc;
  uint4 v0 = *reinterpret_cast<const uint4*>(src);
  uint4 v1 = *reinterpret_cast<const uint4*>(src + 8);
  *reinterpret_cast<uint4*>(&Ts[swz128(sr, sc)]) = v0;
  *reinterpret_cast<uint4*>(&Ts[swz128(sr, sc + 8)]) = v1;
  __syncthreads();
  union { uint4 u[2]; u16 s[16]; } o;
#pragma unroll
  for (int i = 0; i < 16; ++i) o.s[i] = Ts[swz128(sc + i, sr)];
  u16* dst = vT + (long)(bh * 64 + sr) * T_SEQ + tt * 64 + sc;
  reinterpret_cast<uint4*>(dst)[0] = o.u[0];
  reinterpret_cast<uint4*>(dst)[1] = o.u[1];
}

// ---------------- flash attention v4: kv-split waves ----------------
// Grid B*H*(T/64)=1024 blocks, 4 waves. Tile 64q x 64kv per iter; wave w owns
// kv-columns [w*16, w*16+16) and ALL 64 q-rows (Q frags in registers).
// S^T = mfma_16x16x32(Kfrag(w's 16 kv), Qfrag): lane holds S[kv=w16+lh4+r][q=l16].
// P = exp2(S) stays IN REGISTERS (S^T output layout == 16x16x16 B-operand layout).
// O_w^T = mfma_16x16x16(V^Tfrag, Pfrag) accumulates wave's kv-partial O[64d][64q].
// Epilogue: bf16 partials -> LDS (aliased over Q/K/V), cross-wave sum + rowsum.
__global__ __launch_bounds__(256) void attn_kernel(const u16* __restrict__ qkv,
                                                   const u16* __restrict__ vT,
                                                   u16* __restrict__ y) {
  __shared__ char pool[33792];
  u16* Qs = (u16*)pool;               // [64][64] swz128, 8KB
  u16* Ks = (u16*)(pool + 8192);      // [64][64] swz128 (kv rows x d)
  u16* Vs = (u16*)(pool + 16384);     // [64][64] swz128 (d rows x t)
  u16* obuf = (u16*)pool;             // epilogue: [4][64q][64d] swz128 bf16, 32KB
  float* rowsum = (float*)(pool + 32768);  // [4 waves][64 q]

  const int tid = threadIdx.x;
  const int lane = tid & 63, wid = tid >> 6;
  const int l16 = lane & 15, lh = lane >> 4;
  const int bid = blockIdx.x;
  const int qt = bid & 31, h = (bid >> 5) & 15, b = bid >> 9;

  const u16* qbase = qkv + (long)(b * T_SEQ + qt * 64) * 3072 + h * 64;
  const u16* kbase = qkv + (long)(b * T_SEQ) * 3072 + CDIM + h * 64;
  const u16* vtbase = vT + (long)((b * 16 + h) * 64) * T_SEQ;

  const int sr = tid >> 2, sc = (tid & 3) * 16;
  const int ss0 = swz128(sr, sc), ss1 = swz128(sr, sc + 8);

  // hoisted fragment offsets
  int kfo[2];
#pragma unroll
  for (int s = 0; s < 2; ++s) kfo[s] = swz128(wid * 16 + l16, s * 32 + lh * 8);
  int vfo[4];
#pragma unroll
  for (int db = 0; db < 4; ++db) vfo[db] = swz128(db * 16 + l16, wid * 16 + lh * 4);

  {  // stage Q tile [64][64]
    uint4 v0 = *reinterpret_cast<const uint4*>(qbase + (long)sr * 3072 + sc);
    uint4 v1 = *reinterpret_cast<const uint4*>(qbase + (long)sr * 3072 + sc + 8);
    *reinterpret_cast<uint4*>(&Qs[ss0]) = v0;
    *reinterpret_cast<uint4*>(&Qs[ss1]) = v1;
  }
  // prefetch kt=0 K/V into registers
  uint4 kr0 = *reinterpret_cast<const uint4*>(kbase + (long)sr * 3072 + sc);
  uint4 kr1 = *reinterpret_cast<const uint4*>(kbase + (long)sr * 3072 + sc + 8);
  uint4 vr0 = *reinterpret_cast<const uint4*>(vtbase + (long)sr * T_SEQ + sc);
  uint4 vr1 = *reinterpret_cast<const uint4*>(vtbase + (long)sr * T_SEQ + sc + 8);

  __syncthreads();
  // Q B-frags for ALL 64 q-rows (col=q=l16, k=d=lh*8), 4 qb x 2 d-halves
  bf16x8 qf[4][2];
#pragma unroll
  for (int qb = 0; qb < 4; ++qb)
#pragma unroll
    for (int s = 0; s < 2; ++s)
      qf[qb][s] = *reinterpret_cast<const bf16x8*>(&Qs[swz128(qb * 16 + l16, s * 32 + lh * 8)]);

  f32x4 oacc[4][4];   // [db][qb]: lane O[d=db*16+lh*4+r][q=qb*16+l16]
  float lp[4] = {0.f, 0.f, 0.f, 0.f};
#pragma unroll
  for (int db = 0; db < 4; ++db)
#pragma unroll
    for (int qb = 0; qb < 4; ++qb) oacc[db][qb] = f32x4{0.f, 0.f, 0.f, 0.f};

  for (int kt = 0; kt < 32; ++kt) {
    *reinterpret_cast<uint4*>(&Ks[ss0]) = kr0;
    *reinterpret_cast<uint4*>(&Ks[ss1]) = kr1;
    *reinterpret_cast<uint4*>(&Vs[ss0]) = vr0;
    *reinterpret_cast<uint4*>(&Vs[ss1]) = vr1;
    __syncthreads();
    if (kt < 31) {
      const u16* ks = kbase + (long)((kt + 1) * 64 + sr) * 3072 + sc;
      const u16* vs = vtbase + (long)sr * T_SEQ + (kt + 1) * 64 + sc;
      kr0 = *reinterpret_cast<const uint4*>(ks);
      kr1 = *reinterpret_cast<const uint4*>(ks + 8);
      vr0 = *reinterpret_cast<const uint4*>(vs);
      vr1 = *reinterpret_cast<const uint4*>(vs + 8);
    }

    // S^T for wave's 16 kv x all 64 q (log2 units via W-fold)
    bf16x8 kf0 = *reinterpret_cast<const bf16x8*>(&Ks[kfo[0]]);
    bf16x8 kf1 = *reinterpret_cast<const bf16x8*>(&Ks[kfo[1]]);
    f32x4 sacc[4];
#pragma unroll
    for (int qb = 0; qb < 4; ++qb) {
      sacc[qb] = f32x4{0.f, 0.f, 0.f, 0.f};
      sacc[qb] = __builtin_amdgcn_mfma_f32_16x16x32_bf16(kf0, qf[qb][0], sacc[qb], 0, 0, 0);
      sacc[qb] = __builtin_amdgcn_mfma_f32_16x16x32_bf16(kf1, qf[qb][1], sacc[qb], 0, 0, 0);
    }

    // p = 2^s, pack to 16x16x16 B-frags IN REGISTERS (k=kv=lh*4+j matches S^T rows)
    bf16x4 pf[4];
#pragma unroll
    for (int qb = 0; qb < 4; ++qb) {
      float p0 = EXP2(sacc[qb][0]), p1 = EXP2(sacc[qb][1]);
      float p2 = EXP2(sacc[qb][2]), p3 = EXP2(sacc[qb][3]);
      lp[qb] += (p0 + p1) + (p2 + p3);
      union { unsigned u[2]; bf16x4 v; } pu;
      pu.u[0] = pk2bf(p0, p1);
      pu.u[1] = pk2bf(p2, p3);
      pf[qb] = pu.v;
    }

    // V^T A-frags: row d=db*16+l16, k=kv=w*16+lh*4 (b64 reads)
    bf16x4 vf[4];
#pragma unroll
    for (int db = 0; db < 4; ++db)
      vf[db] = *reinterpret_cast<const bf16x4*>(&Vs[vfo[db]]);

    // O_w^T += V^T P^T (k=16)
#pragma unroll
    for (int db = 0; db < 4; ++db)
#pragma unroll
      for (int qb = 0; qb < 4; ++qb)
        oacc[db][qb] = mfma16(vf[db], pf[qb], oacc[db][qb]);
    __syncthreads();
  }

  // per-wave rowsum partials -> LDS
#pragma unroll
  for (int qb = 0; qb < 4; ++qb) {
    float s = lp[qb];
    s += __shfl_xor(s, 16);
    s += __shfl_xor(s, 32);
    if (lane < 16) rowsum[wid * 64 + qb * 16 + lane] = s;
  }

  // wave-partial O (bf16) -> obuf[w][q][d] swz128 (aliases Q/K/V; safe: loop ended
  // with __syncthreads and Q frags were consumed into registers before the loop)
  u16* ob = obuf + wid * 4096;
#pragma unroll
  for (int db = 0; db < 4; ++db) {
#pragma unroll
    for (int qb = 0; qb < 4; ++qb) {
      uint2 w2;
      w2.x = pk2bf(oacc[db][qb][0], oacc[db][qb][1]);
      w2.y = pk2bf(oacc[db][qb][2], oacc[db][qb][3]);
      *reinterpret_cast<uint2*>(&ob[swz128(qb * 16 + l16, db * 16 + lh * 4)]) = w2;
    }
  }
  __syncthreads();

  // final: thread -> q = tid/4, d-chunk = (tid&3)*16; sum 4 wave-partials, normalize
  {
    const int q = tid >> 2, dch = (tid & 3) * 16;
    const float inv = __builtin_amdgcn_rcpf(rowsum[q] + rowsum[64 + q] +
                                            rowsum[128 + q] + rowsum[192 + q]);
    float a[16];
#pragma unroll
    for (int j = 0; j < 16; ++j) a[j] = 0.f;
    const int ri0 = swz128(q, dch), ri1 = swz128(q, dch + 8);
#pragma unroll
    for (int w = 0; w < 4; ++w) {
      const u16* obw = obuf + w * 4096;
      union { uint4 u; u16 s[8]; } r0, r1;
      r0.u = *reinterpret_cast<const uint4*>(&obw[ri0]);
      r1.u = *reinterpret_cast<const uint4*>(&obw[ri1]);
#pragma unroll
      for (int j = 0; j < 8; ++j) {
        a[j] += bf2f(r0.s[j]);
        a[8 + j] += bf2f(r1.s[j]);
      }
    }
    union { uint4 u[2]; u16 s[16]; } o;
#pragma unroll
    for (int j = 0; j < 16; ++j) o.s[j] = f2bf(a[j] * inv);
    u16* yrow = y + (long)(b * T_SEQ + qt * 64 + q) * CDIM + h * 64 + dch;
    *reinterpret_cast<uint4*>(yrow) = o.u[0];
    *reinterpret_cast<uint4*>(yrow + 8) = o.u[1];
  }
}

// ---------------- launch ----------------
extern "C" void kernel_launch(void* const* d_in, const int* in_sizes, int n_in,
                              void* d_out, int out_size, void* d_ws, size_t ws_size,
                              hipStream_t stream) {
  const float* x      = (const float*)d_in[0];  // [2,2048,1024]
  const float* w_attn = (const float*)d_in[1];  // [1024,3072]
  const float* w_proj = (const float*)d_in[2];  // [1024,1024]

  char* ws = (char*)d_ws;
  u16* xb   = (u16*)(ws + 0);           // 8,388,608 B  (dead after qkv GEMM)
  u16* wat  = (u16*)(ws + 8388608);     // 6,291,456 B  [3072][1024]
  u16* wpt  = (u16*)(ws + 14680064);    // 2,097,152 B  [1024][1024]
  u16* qkvb = (u16*)(ws + 16777216);    // 25,165,824 B [4096][3072]
  u16* yb   = (u16*)(ws + 41943040);    // 8,388,608 B  [4096][1024]

  const bool fused = ws_size >= 58720256;  // fused V-transpose needs dedicated vT
  u16* vT = fused ? (u16*)(ws + 50331648) : xb;  // [32*64][2048]

  conv_bf16_kernel<<<4096, 256, 0, stream>>>(x, xb, 1048576);
  transp_conv_kernel<<<96 * 32, 256, 0, stream>>>(w_attn, wat, 1024, 3072, 1024, QSCALE);
  transp_conv_kernel<<<32 * 32, 256, 0, stream>>>(w_proj, wpt, 1024, 1024, 0, 1.0f);
  if (fused) {
    gemm_bt_kernel<2, 128><<<32 * 24, 256, 0, stream>>>(xb, wat, qkvb, vT, 3072, 1024);
  } else {
    gemm_bt_kernel<0, 128><<<32 * 24, 256, 0, stream>>>(xb, wat, qkvb, nullptr, 3072, 1024);
    vtrans_kernel<<<32 * 32, 256, 0, stream>>>(qkvb, vT);
  }
  attn_kernel<<<2 * 16 * 32, 256, 0, stream>>>(qkvb, vT, yb);
  gemm_bt_kernel<1, 64><<<32 * 16, 256, 0, stream>>>(yb, wpt, d_out, nullptr, 1024, 1024);
}